// Round 1
// baseline (1225.244 us; speedup 1.0000x reference)
//
#include <hip/hip_runtime.h>
#include <math.h>

constexpr int NN   = 100000;
constexpr int NE   = 1600000;
constexpr int FIN  = 256;
constexpr int HID  = 64;
constexpr int FOUT = 40;
constexpr float SLOPE = 0.2f;

// float atomic max via signed/unsigned int trick (works across sign mix,
// init must be -inf = 0xFF800000)
__device__ inline void atomicMaxF(float* addr, float v) {
    if (v >= 0.f) atomicMax((int*)addr, __float_as_int(v));
    else          atomicMin((unsigned int*)addr, __float_as_uint(v));
}

// ---------------- GEMM1: z = feat @ W1, fused el = z@al, er = z@ar ---------
// 64-node x 64-col tile, K=256 in 4 slices of 64. 256 thr, 4x4 per thread.
__global__ __launch_bounds__(256) void gemm1_kernel(
    const float* __restrict__ feat, const float* __restrict__ W1,
    const float* __restrict__ al, const float* __restrict__ ar,
    float* __restrict__ z, float* __restrict__ el, float* __restrict__ er)
{
    __shared__ float sT[64 * 65];   // A^T: [k][m], stride 65 (conflict-free)
    __shared__ float sB[64 * 64];   // B:   [k][c]
    const int t  = threadIdx.x;
    const int tm = t >> 4;          // 0..15 -> nodes 4*tm..4*tm+3
    const int tc = t & 15;          // 0..15 -> cols  4*tc..4*tc+3
    const int ntile = blockIdx.x * 64;

    float acc[4][4] = {};

    for (int kt = 0; kt < 4; ++kt) {
        // stage A^T (transpose scatter, 2-way bank alias = free)
        #pragma unroll
        for (int i = 0; i < 4; ++i) {
            int nloc = tm + 16 * i;
            int n = ntile + nloc; if (n >= NN) n = NN - 1;
            float4 f = *(const float4*)&feat[(size_t)n * FIN + kt * 64 + tc * 4];
            int kk = tc * 4;
            sT[(kk + 0) * 65 + nloc] = f.x;
            sT[(kk + 1) * 65 + nloc] = f.y;
            sT[(kk + 2) * 65 + nloc] = f.z;
            sT[(kk + 3) * 65 + nloc] = f.w;
        }
        // stage B slice (contiguous 4096 floats)
        #pragma unroll
        for (int i = 0; i < 4; ++i) {
            int vec = t + 256 * i;
            *(float4*)&sB[vec * 4] = *(const float4*)&W1[kt * 4096 + vec * 4];
        }
        __syncthreads();
        #pragma unroll 8
        for (int k = 0; k < 64; ++k) {
            float a0 = sT[k * 65 + 4 * tm + 0];
            float a1 = sT[k * 65 + 4 * tm + 1];
            float a2 = sT[k * 65 + 4 * tm + 2];
            float a3 = sT[k * 65 + 4 * tm + 3];
            float4 b = *(const float4*)&sB[k * 64 + 4 * tc];
            acc[0][0] += a0 * b.x; acc[0][1] += a0 * b.y; acc[0][2] += a0 * b.z; acc[0][3] += a0 * b.w;
            acc[1][0] += a1 * b.x; acc[1][1] += a1 * b.y; acc[1][2] += a1 * b.z; acc[1][3] += a1 * b.w;
            acc[2][0] += a2 * b.x; acc[2][1] += a2 * b.y; acc[2][2] += a2 * b.z; acc[2][3] += a2 * b.w;
            acc[3][0] += a3 * b.x; acc[3][1] += a3 * b.y; acc[3][2] += a3 * b.z; acc[3][3] += a3 * b.w;
        }
        __syncthreads();
    }

    float alv[4], arv[4];
    #pragma unroll
    for (int j = 0; j < 4; ++j) { alv[j] = al[4 * tc + j]; arv[j] = ar[4 * tc + j]; }

    #pragma unroll
    for (int i = 0; i < 4; ++i) {
        int n = ntile + 4 * tm + i;
        float pl = acc[i][0] * alv[0] + acc[i][1] * alv[1] + acc[i][2] * alv[2] + acc[i][3] * alv[3];
        float pr = acc[i][0] * arv[0] + acc[i][1] * arv[1] + acc[i][2] * arv[2] + acc[i][3] * arv[3];
        // reduce across the 16 lanes sharing this node (xor masks stay in-group)
        #pragma unroll
        for (int off = 8; off >= 1; off >>= 1) {
            pl += __shfl_xor(pl, off);
            pr += __shfl_xor(pr, off);
        }
        if (n < NN) {
            float4 zv = make_float4(acc[i][0], acc[i][1], acc[i][2], acc[i][3]);
            *(float4*)&z[(size_t)n * HID + 4 * tc] = zv;
            if (tc == 0) { el[n] = pl; er[n] = pr; }
        }
    }
}

// ---------------- GEMM2: z2 = h @ W2, fused el2/er2 ------------------------
// one wave per node (K=64, 40 cols). W2 (10KB) lives in L1.
__global__ __launch_bounds__(256) void gemm2_kernel(
    const float* __restrict__ h, const float* __restrict__ W2,
    const float* __restrict__ al, const float* __restrict__ ar,
    float* __restrict__ z2, float* __restrict__ el, float* __restrict__ er)
{
    __shared__ float sh[4][64];
    const int w = threadIdx.x >> 6, lane = threadIdx.x & 63;
    const int n = blockIdx.x * 4 + w;          // NN % 4 == 0
    sh[w][lane] = h[(size_t)n * HID + lane];
    __syncthreads();
    float acc = 0.f;
    if (lane < FOUT) {
        #pragma unroll 8
        for (int k = 0; k < 64; ++k) acc += sh[w][k] * W2[k * FOUT + lane];
    }
    float pl = (lane < FOUT) ? acc * al[lane] : 0.f;
    float pr = (lane < FOUT) ? acc * ar[lane] : 0.f;
    #pragma unroll
    for (int off = 32; off >= 1; off >>= 1) { pl += __shfl_xor(pl, off); pr += __shfl_xor(pr, off); }
    if (lane == 0) { el[n] = pl; er[n] = pr; }
    if (lane < FOUT) z2[(size_t)n * FOUT + lane] = acc;
}

// ---------------- edge passes ----------------------------------------------
__global__ __launch_bounds__(256) void edge_logits_kernel(
    const int* __restrict__ src, const int* __restrict__ dst,
    const float* __restrict__ el, const float* __restrict__ er,
    float* __restrict__ ebuf, float* __restrict__ m)
{
    int i = blockIdx.x * 256 + threadIdx.x;
    if (i >= NE) return;
    int s = src[i], d = dst[i];
    float e = el[s] + er[d];
    e = (e >= 0.f) ? e : SLOPE * e;
    ebuf[i] = e;
    atomicMaxF(&m[d], e);
}

__global__ __launch_bounds__(256) void edge_expsum_kernel(
    const int* __restrict__ dst, float* __restrict__ ebuf,
    const float* __restrict__ m, float* __restrict__ s)
{
    int i = blockIdx.x * 256 + threadIdx.x;
    if (i >= NE) return;
    int d = dst[i];
    float w = expf(ebuf[i] - m[d]);
    ebuf[i] = w;
    atomicAdd(&s[d], w);
}

// one wave per edge, lane = feature column
__global__ __launch_bounds__(256) void edge_agg64_kernel(
    const int* __restrict__ src, const int* __restrict__ dst,
    const float* __restrict__ wbuf, const float* __restrict__ sden,
    const float* __restrict__ z, float* __restrict__ out)
{
    size_t tid = (size_t)blockIdx.x * 256 + threadIdx.x;
    int e = (int)(tid >> 6), lane = (int)(tid & 63);
    if (e >= NE) return;
    int sn = src[e], d = dst[e];
    float alpha = wbuf[e] / sden[d];
    atomicAdd(&out[(size_t)d * 64 + lane], alpha * z[(size_t)sn * 64 + lane]);
}

__global__ __launch_bounds__(256) void edge_agg40_kernel(
    const int* __restrict__ src, const int* __restrict__ dst,
    const float* __restrict__ wbuf, const float* __restrict__ sden,
    const float* __restrict__ z, float* __restrict__ out)
{
    size_t tid = (size_t)blockIdx.x * 256 + threadIdx.x;
    int e = (int)(tid >> 6), lane = (int)(tid & 63);
    if (e >= NE) return;
    int sn = src[e], d = dst[e];
    float alpha = wbuf[e] / sden[d];
    if (lane < FOUT)
        atomicAdd(&out[(size_t)d * FOUT + lane], alpha * z[(size_t)sn * FOUT + lane]);
}

// ---------------- pointwise -------------------------------------------------
__global__ __launch_bounds__(256) void init_kernel(
    float* __restrict__ m1, float* __restrict__ s1,
    float* __restrict__ m2, float* __restrict__ s2)
{
    int i = blockIdx.x * 256 + threadIdx.x;
    if (i >= NN) return;
    m1[i] = -INFINITY; s1[i] = 0.f;
    m2[i] = -INFINITY; s2[i] = 0.f;
}

__global__ __launch_bounds__(256) void bias_relu_kernel(
    float* __restrict__ h, const float* __restrict__ b)
{
    size_t i = (size_t)blockIdx.x * 256 + threadIdx.x;
    if (i >= (size_t)NN * HID) return;
    float v = h[i] + b[i & 63];
    h[i] = (v > 0.f) ? v : 0.f;
}

// per-node log_softmax over 40 cols (one wave per node), bias fused
__global__ __launch_bounds__(256) void logsoftmax_kernel(
    float* __restrict__ out, const float* __restrict__ b2)
{
    const int w = threadIdx.x >> 6, lane = threadIdx.x & 63;
    const int n = blockIdx.x * 4 + w;          // NN % 4 == 0
    float v = (lane < FOUT) ? out[(size_t)n * FOUT + lane] + b2[lane] : -INFINITY;
    float mx = v;
    #pragma unroll
    for (int off = 32; off >= 1; off >>= 1) mx = fmaxf(mx, __shfl_xor(mx, off));
    float ex = (lane < FOUT) ? expf(v - mx) : 0.f;
    float sm = ex;
    #pragma unroll
    for (int off = 32; off >= 1; off >>= 1) sm += __shfl_xor(sm, off);
    if (lane < FOUT) out[(size_t)n * FOUT + lane] = v - mx - logf(sm);
}

extern "C" void kernel_launch(void* const* d_in, const int* in_sizes, int n_in,
                              void* d_out, int out_size, void* d_ws, size_t ws_size,
                              hipStream_t stream) {
    const float* feat = (const float*)d_in[0];
    const int*   src  = (const int*)d_in[1];
    const int*   dst  = (const int*)d_in[2];
    const float* W1   = (const float*)d_in[3];
    const float* b1   = (const float*)d_in[4];
    const float* al1  = (const float*)d_in[5];
    const float* ar1  = (const float*)d_in[6];
    const float* W2   = (const float*)d_in[7];
    const float* b2   = (const float*)d_in[8];
    const float* al2  = (const float*)d_in[9];
    const float* ar2  = (const float*)d_in[10];
    float* out = (float*)d_out;

    float* ws   = (float*)d_ws;
    float* z1   = ws;                          // NN*64  (reused for z2)
    float* h    = z1 + (size_t)NN * HID;       // NN*64
    float* el1  = h + (size_t)NN * HID;
    float* er1  = el1 + NN;
    float* el2  = er1 + NN;
    float* er2  = el2 + NN;
    float* m1   = er2 + NN;
    float* s1   = m1 + NN;
    float* m2   = s1 + NN;
    float* s2   = m2 + NN;
    float* ebuf = s2 + NN;                     // NE
    float* z2   = z1;

    hipMemsetAsync(h, 0, (size_t)NN * HID * sizeof(float), stream);
    hipMemsetAsync(d_out, 0, (size_t)NN * FOUT * sizeof(float), stream);
    init_kernel<<<(NN + 255) / 256, 256, 0, stream>>>(m1, s1, m2, s2);

    // ---- layer 1 ----
    gemm1_kernel<<<(NN + 63) / 64, 256, 0, stream>>>(feat, W1, al1, ar1, z1, el1, er1);
    edge_logits_kernel<<<(NE + 255) / 256, 256, 0, stream>>>(src, dst, el1, er1, ebuf, m1);
    edge_expsum_kernel<<<(NE + 255) / 256, 256, 0, stream>>>(dst, ebuf, m1, s1);
    edge_agg64_kernel<<<(int)(((size_t)NE * 64) / 256), 256, 0, stream>>>(src, dst, ebuf, s1, z1, h);
    bias_relu_kernel<<<(int)(((size_t)NN * HID + 255) / 256), 256, 0, stream>>>(h, b1);

    // ---- layer 2 ----
    gemm2_kernel<<<NN / 4, 256, 0, stream>>>(h, W2, al2, ar2, z2, el2, er2);
    edge_logits_kernel<<<(NE + 255) / 256, 256, 0, stream>>>(src, dst, el2, er2, ebuf, m2);
    edge_expsum_kernel<<<(NE + 255) / 256, 256, 0, stream>>>(dst, ebuf, m2, s2);
    edge_agg40_kernel<<<(int)(((size_t)NE * 64) / 256), 256, 0, stream>>>(src, dst, ebuf, s2, z2, out);
    logsoftmax_kernel<<<NN / 4, 256, 0, stream>>>(out, b2);
}

// Round 2
// 549.087 us; speedup vs baseline: 2.2314x; 2.2314x over previous
//
#include <hip/hip_runtime.h>
#include <math.h>

constexpr int NN   = 100000;
constexpr int NE   = 1600000;
constexpr int FIN  = 256;
constexpr int HID  = 64;
constexpr int FOUT = 40;
constexpr float SLOPE = 0.2f;
constexpr int NB   = (NN + 255) / 256;   // 391 blocks for node-wise scans

// ---------------- GEMM1: z = feat @ W1, fused el = z@al, er = z@ar ---------
// 64-node x 64-col tile, K=256 in 4 slices of 64. 256 thr, 4x4 per thread.
__global__ __launch_bounds__(256) void gemm1_kernel(
    const float* __restrict__ feat, const float* __restrict__ W1,
    const float* __restrict__ al, const float* __restrict__ ar,
    float* __restrict__ z, float* __restrict__ el, float* __restrict__ er)
{
    __shared__ float sT[64 * 65];   // A^T: [k][m], stride 65 (conflict-free)
    __shared__ float sB[64 * 64];   // B:   [k][c]
    const int t  = threadIdx.x;
    const int tm = t >> 4;          // 0..15 -> nodes 4*tm..4*tm+3
    const int tc = t & 15;          // 0..15 -> cols  4*tc..4*tc+3
    const int ntile = blockIdx.x * 64;

    float acc[4][4] = {};

    for (int kt = 0; kt < 4; ++kt) {
        #pragma unroll
        for (int i = 0; i < 4; ++i) {
            int nloc = tm + 16 * i;
            int n = ntile + nloc; if (n >= NN) n = NN - 1;
            float4 f = *(const float4*)&feat[(size_t)n * FIN + kt * 64 + tc * 4];
            int kk = tc * 4;
            sT[(kk + 0) * 65 + nloc] = f.x;
            sT[(kk + 1) * 65 + nloc] = f.y;
            sT[(kk + 2) * 65 + nloc] = f.z;
            sT[(kk + 3) * 65 + nloc] = f.w;
        }
        #pragma unroll
        for (int i = 0; i < 4; ++i) {
            int vec = t + 256 * i;
            *(float4*)&sB[vec * 4] = *(const float4*)&W1[kt * 4096 + vec * 4];
        }
        __syncthreads();
        #pragma unroll 8
        for (int k = 0; k < 64; ++k) {
            float a0 = sT[k * 65 + 4 * tm + 0];
            float a1 = sT[k * 65 + 4 * tm + 1];
            float a2 = sT[k * 65 + 4 * tm + 2];
            float a3 = sT[k * 65 + 4 * tm + 3];
            float4 b = *(const float4*)&sB[k * 64 + 4 * tc];
            acc[0][0] += a0 * b.x; acc[0][1] += a0 * b.y; acc[0][2] += a0 * b.z; acc[0][3] += a0 * b.w;
            acc[1][0] += a1 * b.x; acc[1][1] += a1 * b.y; acc[1][2] += a1 * b.z; acc[1][3] += a1 * b.w;
            acc[2][0] += a2 * b.x; acc[2][1] += a2 * b.y; acc[2][2] += a2 * b.z; acc[2][3] += a2 * b.w;
            acc[3][0] += a3 * b.x; acc[3][1] += a3 * b.y; acc[3][2] += a3 * b.z; acc[3][3] += a3 * b.w;
        }
        __syncthreads();
    }

    float alv[4], arv[4];
    #pragma unroll
    for (int j = 0; j < 4; ++j) { alv[j] = al[4 * tc + j]; arv[j] = ar[4 * tc + j]; }

    #pragma unroll
    for (int i = 0; i < 4; ++i) {
        int n = ntile + 4 * tm + i;
        float pl = acc[i][0] * alv[0] + acc[i][1] * alv[1] + acc[i][2] * alv[2] + acc[i][3] * alv[3];
        float pr = acc[i][0] * arv[0] + acc[i][1] * arv[1] + acc[i][2] * arv[2] + acc[i][3] * arv[3];
        #pragma unroll
        for (int off = 8; off >= 1; off >>= 1) {
            pl += __shfl_xor(pl, off);
            pr += __shfl_xor(pr, off);
        }
        if (n < NN) {
            float4 zv = make_float4(acc[i][0], acc[i][1], acc[i][2], acc[i][3]);
            *(float4*)&z[(size_t)n * HID + 4 * tc] = zv;
            if (tc == 0) { el[n] = pl; er[n] = pr; }
        }
    }
}

// ---------------- GEMM2: z2 = h @ W2, fused el2/er2 ------------------------
__global__ __launch_bounds__(256) void gemm2_kernel(
    const float* __restrict__ h, const float* __restrict__ W2,
    const float* __restrict__ al, const float* __restrict__ ar,
    float* __restrict__ z2, float* __restrict__ el, float* __restrict__ er)
{
    __shared__ float sh[4][64];
    const int w = threadIdx.x >> 6, lane = threadIdx.x & 63;
    const int n = blockIdx.x * 4 + w;          // NN % 4 == 0
    sh[w][lane] = h[(size_t)n * HID + lane];
    __syncthreads();
    float acc = 0.f;
    if (lane < FOUT) {
        #pragma unroll 8
        for (int k = 0; k < 64; ++k) acc += sh[w][k] * W2[k * FOUT + lane];
    }
    float pl = (lane < FOUT) ? acc * al[lane] : 0.f;
    float pr = (lane < FOUT) ? acc * ar[lane] : 0.f;
    #pragma unroll
    for (int off = 32; off >= 1; off >>= 1) { pl += __shfl_xor(pl, off); pr += __shfl_xor(pr, off); }
    if (lane == 0) { el[n] = pl; er[n] = pr; }
    if (lane < FOUT) z2[(size_t)n * FOUT + lane] = acc;
}

// ---------------- CSR build -------------------------------------------------
__global__ __launch_bounds__(256) void hist_kernel(
    const int* __restrict__ dst, int* __restrict__ deg)
{
    int i = blockIdx.x * 256 + threadIdx.x;
    if (i < NE) atomicAdd(&deg[dst[i]], 1);
}

__global__ __launch_bounds__(256) void scan_reduce_kernel(
    const int* __restrict__ deg, int* __restrict__ bsum)
{
    __shared__ int tmp[256];
    int idx = blockIdx.x * 256 + threadIdx.x;
    int v = (idx < NN) ? deg[idx] : 0;
    tmp[threadIdx.x] = v; __syncthreads();
    for (int off = 128; off >= 1; off >>= 1) {
        if (threadIdx.x < off) tmp[threadIdx.x] += tmp[threadIdx.x + off];
        __syncthreads();
    }
    if (threadIdx.x == 0) bsum[blockIdx.x] = tmp[0];
}

__global__ __launch_bounds__(512) void scan_top_kernel(
    const int* __restrict__ bsum, int* __restrict__ bofs, int* __restrict__ row_ptr)
{
    __shared__ int tmp[512];
    int t = threadIdx.x;
    int v = (t < NB) ? bsum[t] : 0;
    tmp[t] = v; __syncthreads();
    for (int off = 1; off < 512; off <<= 1) {
        int x = (t >= off) ? tmp[t - off] : 0;
        __syncthreads();
        tmp[t] += x;
        __syncthreads();
    }
    int excl = tmp[t] - v;
    if (t < NB) bofs[t] = excl;
    if (t == NB - 1) row_ptr[NN] = excl + v;  // total = NE
}

__global__ __launch_bounds__(256) void scan_final_kernel(
    const int* __restrict__ deg, const int* __restrict__ bofs,
    int* __restrict__ row_ptr)
{
    __shared__ int tmp[256];
    int t = threadIdx.x;
    int idx = blockIdx.x * 256 + t;
    int v = (idx < NN) ? deg[idx] : 0;
    tmp[t] = v; __syncthreads();
    for (int off = 1; off < 256; off <<= 1) {
        int x = (t >= off) ? tmp[t - off] : 0;
        __syncthreads();
        tmp[t] += x;
        __syncthreads();
    }
    if (idx < NN) row_ptr[idx] = bofs[blockIdx.x] + tmp[t] - v;
}

__global__ __launch_bounds__(256) void scatter_kernel(
    const int* __restrict__ src, const int* __restrict__ dst,
    const int* __restrict__ row_ptr, int* __restrict__ cnt,
    int* __restrict__ esrc)
{
    int i = blockIdx.x * 256 + threadIdx.x;
    if (i >= NE) return;
    int d = dst[i];
    int pos = row_ptr[d] + atomicAdd(&cnt[d], 1);
    esrc[pos] = src[i];
}

// ---------------- fused per-destination GAT gather -------------------------
// One wave per destination node; lane = feature for aggregation, lane = edge
// for logits. Wave-synchronous LDS staging (per-wave slice, no barriers).
template<int F, bool FINAL_LAYER>
__global__ __launch_bounds__(256) void gat_gather_kernel(
    const int* __restrict__ row_ptr, const int* __restrict__ esrc,
    const float* __restrict__ el, const float* __restrict__ er,
    const float* __restrict__ z, const float* __restrict__ bias,
    float* __restrict__ out)
{
    __shared__ float sw[4][64];
    __shared__ int   ssn[4][64];
    const int w = threadIdx.x >> 6, lane = threadIdx.x & 63;
    const int d = blockIdx.x * 4 + w;          // NN % 4 == 0
    const int r0 = row_ptr[d], r1 = row_ptr[d + 1];
    const float erd = er[d];

    // phase 1: row max of leaky_relu(el[src] + er[d])
    float m = -INFINITY;
    for (int e = r0 + lane; e < r1; e += 64) {
        float v = el[esrc[e]] + erd;
        v = (v >= 0.f) ? v : SLOPE * v;
        m = fmaxf(m, v);
    }
    #pragma unroll
    for (int off = 32; off >= 1; off >>= 1) m = fmaxf(m, __shfl_xor(m, off));

    // phase 2: chunked exp/sum + feature gather-accumulate
    float s = 0.f;
    float accv = 0.f;
    for (int base = r0; base < r1; base += 64) {
        int e = base + lane;
        float wv = 0.f; int sn = 0;
        if (e < r1) {
            sn = esrc[e];
            float v = el[sn] + erd;
            v = (v >= 0.f) ? v : SLOPE * v;
            wv = __expf(v - m);
        }
        sw[w][lane] = wv; ssn[w][lane] = sn;
        s += wv;
        int cnt = r1 - base; if (cnt > 64) cnt = 64;
        if (lane < F) {
            int j = 0;
            for (; j + 4 <= cnt; j += 4) {
                float w0 = sw[w][j],     w1 = sw[w][j + 1];
                float w2 = sw[w][j + 2], w3 = sw[w][j + 3];
                int   s0 = ssn[w][j],     s1 = ssn[w][j + 1];
                int   s2 = ssn[w][j + 2], s3 = ssn[w][j + 3];
                float z0 = z[(size_t)s0 * F + lane];
                float z1 = z[(size_t)s1 * F + lane];
                float z2 = z[(size_t)s2 * F + lane];
                float z3 = z[(size_t)s3 * F + lane];
                accv += w0 * z0; accv += w1 * z1; accv += w2 * z2; accv += w3 * z3;
            }
            for (; j < cnt; ++j)
                accv += sw[w][j] * z[(size_t)ssn[w][j] * F + lane];
        }
    }
    #pragma unroll
    for (int off = 32; off >= 1; off >>= 1) s += __shfl_xor(s, off);

    float res = (r1 > r0) ? (accv / s) : 0.f;

    if (!FINAL_LAYER) {
        // + bias, relu
        if (lane < F) {
            float v = res + bias[lane];
            out[(size_t)d * F + lane] = (v > 0.f) ? v : 0.f;
        }
    } else {
        // + bias, log_softmax over F cols
        float v = (lane < F) ? res + bias[lane] : -INFINITY;
        float mx = v;
        #pragma unroll
        for (int off = 32; off >= 1; off >>= 1) mx = fmaxf(mx, __shfl_xor(mx, off));
        float ex = (lane < F) ? __expf(v - mx) : 0.f;
        float sm = ex;
        #pragma unroll
        for (int off = 32; off >= 1; off >>= 1) sm += __shfl_xor(sm, off);
        if (lane < F) out[(size_t)d * F + lane] = v - mx - __logf(sm);
    }
}

extern "C" void kernel_launch(void* const* d_in, const int* in_sizes, int n_in,
                              void* d_out, int out_size, void* d_ws, size_t ws_size,
                              hipStream_t stream) {
    const float* feat = (const float*)d_in[0];
    const int*   src  = (const int*)d_in[1];
    const int*   dst  = (const int*)d_in[2];
    const float* W1   = (const float*)d_in[3];
    const float* b1   = (const float*)d_in[4];
    const float* al1  = (const float*)d_in[5];
    const float* ar1  = (const float*)d_in[6];
    const float* W2   = (const float*)d_in[7];
    const float* b2   = (const float*)d_in[8];
    const float* al2  = (const float*)d_in[9];
    const float* ar2  = (const float*)d_in[10];
    float* out = (float*)d_out;

    float* ws    = (float*)d_ws;
    float* z1    = ws;                          // NN*64 (reused for z2)
    float* h     = z1 + (size_t)NN * HID;       // NN*64
    float* el1   = h + (size_t)NN * HID;
    float* er1   = el1 + NN;
    float* el2   = er1 + NN;
    float* er2   = el2 + NN;
    int*   deg   = (int*)(er2 + NN);            // NN
    int*   cnt   = deg + NN;                    // NN
    int*   rowp  = cnt + NN;                    // NN+1
    int*   bsum  = rowp + NN + 1;               // NB
    int*   bofs  = bsum + NB;                   // NB
    int*   esrc  = bofs + NB;                   // NE
    float* z2    = z1;

    // ---- CSR build (every call; ws is re-poisoned) ----
    hipMemsetAsync(deg, 0, 2 * NN * sizeof(int), stream);  // deg + cnt
    hist_kernel<<<(NE + 255) / 256, 256, 0, stream>>>(dst, deg);
    scan_reduce_kernel<<<NB, 256, 0, stream>>>(deg, bsum);
    scan_top_kernel<<<1, 512, 0, stream>>>(bsum, bofs, rowp);
    scan_final_kernel<<<NB, 256, 0, stream>>>(deg, bofs, rowp);
    scatter_kernel<<<(NE + 255) / 256, 256, 0, stream>>>(src, dst, rowp, cnt, esrc);

    // ---- layer 1 ----
    gemm1_kernel<<<(NN + 63) / 64, 256, 0, stream>>>(feat, W1, al1, ar1, z1, el1, er1);
    gat_gather_kernel<HID, false><<<NN / 4, 256, 0, stream>>>(rowp, esrc, el1, er1, z1, b1, h);

    // ---- layer 2 ----
    gemm2_kernel<<<NN / 4, 256, 0, stream>>>(h, W2, al2, ar2, z2, el2, er2);
    gat_gather_kernel<FOUT, true><<<NN / 4, 256, 0, stream>>>(rowp, esrc, el2, er2, z2, b2, out);
}